// Round 1
// baseline (173.112 us; speedup 1.0000x reference)
//
#include <hip/hip_runtime.h>
#include <cstddef>

#define NN 4096   // nodes
#define NL 8      // layers
#define ND 128    // feature dim

// ---------------------------------------------------------------------------
// Kernel 1: deg[l*NN+i] = sum_j adj[l,i,j] + 1   (row sums, full 512MB read)
// One 256-thread block per row (16KB), int4 vector loads, block reduce.
// ---------------------------------------------------------------------------
__global__ __launch_bounds__(256) void deg_kernel(const int* __restrict__ adj,
                                                  float* __restrict__ deg) {
  const size_t row = blockIdx.x;  // 0 .. NL*NN-1
  const int4* __restrict__ p =
      reinterpret_cast<const int4*>(adj + row * (size_t)NN);
  int s = 0;
#pragma unroll
  for (int t = 0; t < 4; ++t) {
    int4 v = p[threadIdx.x + t * 256];
    s += v.x + v.y + v.z + v.w;
  }
  // wave reduce (64 lanes)
  for (int off = 32; off > 0; off >>= 1) s += __shfl_down(s, off, 64);
  __shared__ int ws[4];
  if ((threadIdx.x & 63) == 0) ws[threadIdx.x >> 6] = s;
  __syncthreads();
  if (threadIdx.x == 0)
    deg[row] = (float)(ws[0] + ws[1] + ws[2] + ws[3]) + 1.0f;
}

// ---------------------------------------------------------------------------
// Kernel 2: src[l*NN+j] = max( largest i>j with adj[l,i,j]==1 , j )
// Descending scan over i with block-wide early exit; random 0/1 data means
// nearly every column resolves within the first 32-row chunk.
// ---------------------------------------------------------------------------
__global__ __launch_bounds__(256) void src_kernel(const int* __restrict__ adj,
                                                  int* __restrict__ src) {
  const int l = blockIdx.y;
  const int j = blockIdx.x * 256 + threadIdx.x;
  const int* __restrict__ A = adj + (size_t)l * NN * NN + j;
  int cur = j;       // diagonal always in mask
  bool found = false;
  int i = NN - 1;
  while (true) {
    int iend = (i - 32 > 0) ? (i - 32) : 0;
    for (; i > iend; --i) {
      if (!found && i > j) {
        if (A[(size_t)i * NN] != 0) { cur = i; found = true; }
      }
    }
    if (__syncthreads_and((int)(found || i <= j)) || i == 0) break;
  }
  src[l * NN + j] = cur;
}

// ---------------------------------------------------------------------------
// Kernel 3: out[j,l,d] = rsqrt(deg[l,src]*deg[l,j]) * sum_e W[d,e]*feat[src,l,e]
// W staged once per block in LDS with stride 129 (bank = (d+e)%32, 2-way free).
// Block = 256 threads = two 128-thread halves, each half does one (l,j) pair;
// 16 pairs per block amortize the W load.
// ---------------------------------------------------------------------------
#define PAIRS 16
__global__ __launch_bounds__(256) void out_kernel(
    const float* __restrict__ feature, const float* __restrict__ W,
    const float* __restrict__ deg, const int* __restrict__ src,
    float* __restrict__ out) {
  __shared__ float Wl[128 * 129];   // ~66KB, 2 blocks/CU
  __shared__ float fbuf[2][128];
  __shared__ float sc[2];

  for (int idx = threadIdx.x; idx < 128 * 128; idx += 256)
    Wl[(idx >> 7) * 129 + (idx & 127)] = W[idx];
  __syncthreads();

  const int l = blockIdx.y;
  const int jbase = blockIdx.x * PAIRS;
  const int half = threadIdx.x >> 7;  // 0 or 1
  const int d = threadIdx.x & 127;
  const float* __restrict__ wrow = &Wl[d * 129];

  for (int p = 0; p < PAIRS; p += 2) {
    const int j = jbase + p + half;
    const int s = src[l * NN + j];
    if (d < 32) {
      const float4* fp =
          reinterpret_cast<const float4*>(feature + ((size_t)s * NL + l) * ND);
      reinterpret_cast<float4*>(fbuf[half])[d] = fp[d];
    }
    if (d == 0) sc[half] = rsqrtf(deg[l * NN + s] * deg[l * NN + j]);
    __syncthreads();
    float acc = 0.0f;
#pragma unroll 8
    for (int e = 0; e < 128; ++e) acc += wrow[e] * fbuf[half][e];
    out[((size_t)j * NL + l) * ND + d] = acc * sc[half];
    __syncthreads();  // protect fbuf/sc before next pair
  }
}

// ---------------------------------------------------------------------------
extern "C" void kernel_launch(void* const* d_in, const int* in_sizes, int n_in,
                              void* d_out, int out_size, void* d_ws,
                              size_t ws_size, hipStream_t stream) {
  const float* feature = (const float*)d_in[0];   // [NN, NL, ND] f32
  const float* W       = (const float*)d_in[1];   // [ND, ND]     f32
  const int*   adj     = (const int*)d_in[2];     // [NL, NN, NN] i32
  float* out = (float*)d_out;                     // [NN, NL, ND] f32

  float* deg = (float*)d_ws;                                        // NL*NN f32
  int*   src = (int*)((char*)d_ws + (size_t)NL * NN * sizeof(float)); // NL*NN i32

  deg_kernel<<<NL * NN, 256, 0, stream>>>(adj, deg);
  src_kernel<<<dim3(NN / 256, NL), 256, 0, stream>>>(adj, src);
  out_kernel<<<dim3(NN / PAIRS, NL), 256, 0, stream>>>(feature, W, deg, src, out);
}

// Round 2
// 131.581 us; speedup vs baseline: 1.3156x; 1.3156x over previous
//
#include <hip/hip_runtime.h>
#include <cstddef>

#define NN 4096   // nodes
#define NL 8      // layers
#define ND 128    // feature dim

#define SRC_BLOCKS (NL * (NN / 256))   // 128 src blocks, dispatched FIRST

// ---------------------------------------------------------------------------
// Fused kernel: blocks [0,128) compute src (latency-bound, overlaps with the
// BW-bound deg stream); blocks [128, 128+32768) compute deg row sums.
// ---------------------------------------------------------------------------
__global__ __launch_bounds__(256) void degsrc_kernel(const int* __restrict__ adj,
                                                     float* __restrict__ deg,
                                                     int* __restrict__ src) {
  if (blockIdx.x < SRC_BLOCKS) {
    // ---- src[l*NN+j] = max( largest i>j with adj[l,i,j]!=0 , j ) ----
    const int bid = blockIdx.x;
    const int l = bid >> 4;                    // 16 blocks per layer
    const int j = ((bid & 15) << 8) + threadIdx.x;
    const int* __restrict__ A = adj + (size_t)l * NN * NN + j;
    int cur = j;
    bool found = false;
    int itop = NN - 1;
    while (true) {
      int ibot = itop - 31;
      if (ibot < 0) ibot = 0;
      // 32 unconditional, independent loads -> single latency round
      int best = -1;
#pragma unroll
      for (int k = 0; k < 32; ++k) {
        int i = itop - k;
        int a = (i >= ibot) ? A[(size_t)i * NN] : 0;
        int c = (a != 0 && i > j) ? i : -1;
        if (c > best) best = c;
      }
      if (!found && best >= 0) { cur = best; found = true; }
      bool done = found || (ibot <= j + 1);
      if (__syncthreads_and((int)done)) break;
      itop = ibot - 1;
    }
    src[l * NN + j] = cur;
  } else {
    // ---- deg[row] = sum(adj row) + 1 ----
    const size_t row = blockIdx.x - SRC_BLOCKS;
    const int4* __restrict__ p =
        reinterpret_cast<const int4*>(adj + row * (size_t)NN);
    int s = 0;
#pragma unroll
    for (int t = 0; t < 4; ++t) {
      int4 v = p[threadIdx.x + t * 256];
      s += v.x + v.y + v.z + v.w;
    }
    for (int off = 32; off > 0; off >>= 1) s += __shfl_down(s, off, 64);
    __shared__ int ws[4];
    if ((threadIdx.x & 63) == 0) ws[threadIdx.x >> 6] = s;
    __syncthreads();
    if (threadIdx.x == 0)
      deg[row] = (float)(ws[0] + ws[1] + ws[2] + ws[3]) + 1.0f;
  }
}

// ---------------------------------------------------------------------------
// out[j,l,d] = rsqrt(deg[l,src]*deg[l,j]) * sum_e W[d,e]*feat[src,l,e]
// Register-blocked: 32-lane group handles JB=4 j's; each thread 4 d's
// (u, u+32, u+64, u+96) -> 16 accumulators; per e-pair: 8 ds_read_b64 for
// 32 FMAs (0.25 LDS instr / FMA). W at stride 130: 2-way bank alias (free),
// 8B-aligned float2 reads.
// ---------------------------------------------------------------------------
#define JB 4
#define NGRP 8                 // 256 threads = 8 groups of 32 lanes
#define JPB (JB * NGRP)        // 32 j's per pass
#define PASSES 2               // 64 j's per block
#define WS 130

__global__ __launch_bounds__(256) void out_kernel(
    const float* __restrict__ feature, const float* __restrict__ W,
    const float* __restrict__ deg, const int* __restrict__ src,
    float* __restrict__ out) {
  __shared__ float Wl[128 * WS];       // 66.6 KB
  __shared__ float fbuf[JPB][ND];      // 16 KB
  __shared__ float sc[JPB];

  for (int idx = threadIdx.x; idx < 128 * 128; idx += 256) {
    int d = idx >> 7, e = idx & 127;
    Wl[d * WS + e] = W[idx];
  }

  const int l = blockIdx.y;
  const int g = threadIdx.x >> 5;
  const int u = threadIdx.x & 31;

  for (int pass = 0; pass < PASSES; ++pass) {
    const int jbase = (blockIdx.x * PASSES + pass) * JPB;
    __syncthreads();  // W staged / previous pass done reading fbuf
    for (int idx = threadIdx.x; idx < JPB * (ND / 4); idx += 256) {
      int jj = idx >> 5;          // 32 float4 per j
      int q = idx & 31;
      int s = src[l * NN + jbase + jj];
      reinterpret_cast<float4*>(fbuf[jj])[q] =
          reinterpret_cast<const float4*>(feature + ((size_t)s * NL + l) * ND)[q];
    }
    if (threadIdx.x < JPB) {
      int j = jbase + threadIdx.x;
      int s = src[l * NN + j];
      sc[threadIdx.x] = rsqrtf(deg[l * NN + s] * deg[l * NN + j]);
    }
    __syncthreads();

    float acc[JB][4];
#pragma unroll
    for (int b = 0; b < JB; ++b)
#pragma unroll
      for (int k = 0; k < 4; ++k) acc[b][k] = 0.0f;

    const float* __restrict__ frow = fbuf[g * JB];
#pragma unroll 4
    for (int e = 0; e < ND; e += 2) {
      float2 w0 = *reinterpret_cast<const float2*>(&Wl[(u)*WS + e]);
      float2 w1 = *reinterpret_cast<const float2*>(&Wl[(u + 32) * WS + e]);
      float2 w2 = *reinterpret_cast<const float2*>(&Wl[(u + 64) * WS + e]);
      float2 w3 = *reinterpret_cast<const float2*>(&Wl[(u + 96) * WS + e]);
#pragma unroll
      for (int b = 0; b < JB; ++b) {
        float2 f = *reinterpret_cast<const float2*>(&frow[b * ND + e]);
        acc[b][0] += w0.x * f.x + w0.y * f.y;
        acc[b][1] += w1.x * f.x + w1.y * f.y;
        acc[b][2] += w2.x * f.x + w2.y * f.y;
        acc[b][3] += w3.x * f.x + w3.y * f.y;
      }
    }

#pragma unroll
    for (int b = 0; b < JB; ++b) {
      const int j = jbase + g * JB + b;
      const float s = sc[g * JB + b];
      float* o = out + ((size_t)j * NL + l) * ND;
      o[u] = acc[b][0] * s;
      o[u + 32] = acc[b][1] * s;
      o[u + 64] = acc[b][2] * s;
      o[u + 96] = acc[b][3] * s;
    }
  }
}

// ---------------------------------------------------------------------------
extern "C" void kernel_launch(void* const* d_in, const int* in_sizes, int n_in,
                              void* d_out, int out_size, void* d_ws,
                              size_t ws_size, hipStream_t stream) {
  const float* feature = (const float*)d_in[0];   // [NN, NL, ND] f32
  const float* W       = (const float*)d_in[1];   // [ND, ND]     f32
  const int*   adj     = (const int*)d_in[2];     // [NL, NN, NN] i32
  float* out = (float*)d_out;                     // [NN, NL, ND] f32

  float* deg = (float*)d_ws;                                          // NL*NN f32
  int*   src = (int*)((char*)d_ws + (size_t)NL * NN * sizeof(float)); // NL*NN i32

  degsrc_kernel<<<SRC_BLOCKS + NL * NN, 256, 0, stream>>>(adj, deg, src);
  out_kernel<<<dim3(NN / (PASSES * JPB), NL), 256, 0, stream>>>(feature, W, deg,
                                                                src, out);
}

// Round 3
// 113.107 us; speedup vs baseline: 1.5305x; 1.1633x over previous
//
#include <hip/hip_runtime.h>
#include <cstddef>

#define NN 4096   // nodes
#define NL 8      // layers
#define ND 128    // feature dim

#define SRC_BLOCKS (NL * (NN / 256))   // 128 src blocks, dispatched FIRST

typedef int   int4v   __attribute__((ext_vector_type(4)));
typedef float float4v __attribute__((ext_vector_type(4)));

// ---------------------------------------------------------------------------
// Fused kernel: blocks [0,128) compute src (latency-bound, overlaps with the
// BW-bound deg stream); remaining blocks compute deg row sums (2 rows/block,
// non-temporal loads — adj is streamed once, don't pollute L2/L3).
// ---------------------------------------------------------------------------
__global__ __launch_bounds__(256) void degsrc_kernel(const int* __restrict__ adj,
                                                     float* __restrict__ deg,
                                                     int* __restrict__ src) {
  if (blockIdx.x < SRC_BLOCKS) {
    // ---- src[l*NN+j] = max( largest i>j with adj[l,i,j]!=0 , j ) ----
    const int bid = blockIdx.x;
    const int l = bid >> 4;                    // 16 blocks per layer
    const int j = ((bid & 15) << 8) + threadIdx.x;
    const int* __restrict__ A = adj + (size_t)l * NN * NN + j;
    int cur = j;
    bool found = false;
    int itop = NN - 1;
    while (true) {
      int ibot = itop - 31;
      if (ibot < 0) ibot = 0;
      int best = -1;
#pragma unroll
      for (int k = 0; k < 32; ++k) {
        int i = itop - k;
        int a = (i >= ibot) ? A[(size_t)i * NN] : 0;
        int c = (a != 0 && i > j) ? i : -1;
        if (c > best) best = c;
      }
      if (!found && best >= 0) { cur = best; found = true; }
      bool done = found || (ibot <= j + 1);
      if (__syncthreads_and((int)done)) break;
      itop = ibot - 1;
    }
    src[l * NN + j] = cur;
  } else {
    // ---- deg[row] = sum(adj row) + 1 ; 2 rows per block ----
    const size_t row2 = (size_t)(blockIdx.x - SRC_BLOCKS) * 2;
    const int r = threadIdx.x >> 7;   // 0/1: which row
    const int t = threadIdx.x & 127;
    const int4v* __restrict__ p =
        reinterpret_cast<const int4v*>(adj + (row2 + r) * (size_t)NN);
    int s = 0;
#pragma unroll
    for (int k = 0; k < 8; ++k) {
      int4v v = __builtin_nontemporal_load(&p[t + k * 128]);
      s += v.x + v.y + v.z + v.w;
    }
    for (int off = 32; off > 0; off >>= 1) s += __shfl_down(s, off, 64);
    __shared__ int ws[4];
    if ((threadIdx.x & 63) == 0) ws[threadIdx.x >> 6] = s;
    __syncthreads();
    if (threadIdx.x == 0)   deg[row2]     = (float)(ws[0] + ws[1]) + 1.0f;
    if (threadIdx.x == 128) deg[row2 + 1] = (float)(ws[2] + ws[3]) + 1.0f;
  }
}

// ---------------------------------------------------------------------------
// out[j,l,d] = rsqrt(deg[l,src]*deg[l,j]) * sum_e W[d,e]*feat[src,l,e]
// 8x8 register tile: 16-lane group u handles d in {u,u+16,...,u+112}, group g
// handles j in {g*8..g*8+7}. float4 LDS reads; XOR swizzle on quad index:
//   W row d:   quad stored at eq ^ (d&7)   -> 2-way/broadcast = free
//   fb row j:  quad stored at eq ^ ((j>>3)&7) -> 4 groups hit 4 bank-quads
// LDS = 64KB W + 64KB fb = 128KB, 1 block/CU; 256 blocks = exactly 1 per CU.
// LDS bytes/MAC = 1.0 -> FMA-bound (~16k cyc/CU).
// ---------------------------------------------------------------------------
#define JT 128   // j per block
__global__ __launch_bounds__(256, 1) void out_kernel(
    const float* __restrict__ feature, const float* __restrict__ W,
    const float* __restrict__ deg, const int* __restrict__ src,
    float* __restrict__ out) {
  __shared__ float Wl[128 * 128];
  __shared__ float fb[JT * 128];

  const int l = blockIdx.y;
  const int jbase = blockIdx.x * JT;

  // stage W (swizzled quads)
  for (int q = threadIdx.x; q < 128 * 32; q += 256) {
    int dd = q >> 5, eq = q & 31;
    float4v v = reinterpret_cast<const float4v*>(W)[q];
    *reinterpret_cast<float4v*>(&Wl[dd * 128 + 4 * (eq ^ (dd & 7))]) = v;
  }
  // stage gathered feature rows (swizzled quads)
  for (int q = threadIdx.x; q < JT * 32; q += 256) {
    int jj = q >> 5, eq = q & 31;
    int s = src[l * NN + jbase + jj];
    float4v v = reinterpret_cast<const float4v*>(
        feature + ((size_t)s * NL + l) * ND)[eq];
    *reinterpret_cast<float4v*>(&fb[jj * 128 + 4 * (eq ^ ((jj >> 3) & 7))]) = v;
  }
  __syncthreads();

  const int u = threadIdx.x & 15;    // d lane
  const int g = threadIdx.x >> 4;    // j group 0..15
  const int wsw = u & 7;
  const int fsw = g & 7;

  float acc[8][8];
#pragma unroll
  for (int dd = 0; dd < 8; ++dd)
#pragma unroll
    for (int jj = 0; jj < 8; ++jj) acc[dd][jj] = 0.0f;

#pragma unroll 2
  for (int eq = 0; eq < 32; ++eq) {
    float4v w[8], f[8];
#pragma unroll
    for (int dd = 0; dd < 8; ++dd)
      w[dd] = *reinterpret_cast<const float4v*>(
          &Wl[(u + dd * 16) * 128 + 4 * (eq ^ wsw)]);
#pragma unroll
    for (int jj = 0; jj < 8; ++jj)
      f[jj] = *reinterpret_cast<const float4v*>(
          &fb[(g * 8 + jj) * 128 + 4 * (eq ^ fsw)]);
#pragma unroll
    for (int dd = 0; dd < 8; ++dd)
#pragma unroll
      for (int jj = 0; jj < 8; ++jj)
        acc[dd][jj] += w[dd].x * f[jj].x + w[dd].y * f[jj].y +
                       w[dd].z * f[jj].z + w[dd].w * f[jj].w;
  }

#pragma unroll
  for (int jj = 0; jj < 8; ++jj) {
    const int j = jbase + g * 8 + jj;
    const int s = src[l * NN + j];
    const float scj = rsqrtf(deg[l * NN + s] * deg[l * NN + j]);
    float* o = out + ((size_t)j * NL + l) * ND;
#pragma unroll
    for (int dd = 0; dd < 8; ++dd) o[u + dd * 16] = acc[dd][jj] * scj;
  }
}

// ---------------------------------------------------------------------------
extern "C" void kernel_launch(void* const* d_in, const int* in_sizes, int n_in,
                              void* d_out, int out_size, void* d_ws,
                              size_t ws_size, hipStream_t stream) {
  const float* feature = (const float*)d_in[0];   // [NN, NL, ND] f32
  const float* W       = (const float*)d_in[1];   // [ND, ND]     f32
  const int*   adj     = (const int*)d_in[2];     // [NL, NN, NN] i32
  float* out = (float*)d_out;                     // [NN, NL, ND] f32

  float* deg = (float*)d_ws;                                          // NL*NN f32
  int*   src = (int*)((char*)d_ws + (size_t)NL * NN * sizeof(float)); // NL*NN i32

  degsrc_kernel<<<SRC_BLOCKS + NL * NN / 2, 256, 0, stream>>>(adj, deg, src);
  out_kernel<<<dim3(NN / JT, NL), 256, 0, stream>>>(feature, W, deg, src, out);
}

// Round 4
// 108.378 us; speedup vs baseline: 1.5973x; 1.0436x over previous
//
#include <hip/hip_runtime.h>
#include <cstddef>

#define NN 4096   // nodes
#define NL 8      // layers
#define ND 128    // feature dim

#define SRC_BLOCKS (NL * (NN / 256))   // 128 src blocks, dispatched FIRST

typedef int   int4v   __attribute__((ext_vector_type(4)));
typedef float float4v __attribute__((ext_vector_type(4)));

// ws layout:
//   deg : [NL*NN]   f32  @ 0         (128 KB)
//   src : [NL*NN]   i32  @ 131072    (128 KB)
//   used: [128*128] u32  @ 262144    (64 KB; one private 128-word region per
//                                     src block -> no races, fully rewritten
//                                     every call -> no zeroing pass needed)
//   Wf  : [NL*NN*ND] f32 @ 327680    (16.8 MB; only "used" rows are written,
//                                     and only used rows are ever read)

// ---------------------------------------------------------------------------
// Fused kernel: blocks [0,128) compute src + used-bits (latency-bound,
// overlaps with the BW-bound deg stream); remaining blocks do deg row sums
// (2 rows/block, non-temporal loads — adj is streamed exactly once).
// ---------------------------------------------------------------------------
__global__ __launch_bounds__(256) void degsrc_kernel(const int* __restrict__ adj,
                                                     float* __restrict__ deg,
                                                     int* __restrict__ src,
                                                     unsigned* __restrict__ used) {
  __shared__ unsigned lmask[128];
  __shared__ int ws[4];

  if (blockIdx.x < SRC_BLOCKS) {
    // ---- src[l*NN+j] = max( largest i>j with adj[l,i,j]!=0 , j ) ----
    const int bid = blockIdx.x;
    const int l = bid >> 4;                    // 16 blocks per layer
    const int j = ((bid & 15) << 8) + threadIdx.x;
    const int* __restrict__ A = adj + (size_t)l * NN * NN + j;
    if (threadIdx.x < 128) lmask[threadIdx.x] = 0u;
    __syncthreads();
    int cur = j;
    bool found = false;
    int itop = NN - 1;
    while (true) {
      int ibot = itop - 31;
      if (ibot < 0) ibot = 0;
      int best = -1;
#pragma unroll
      for (int k = 0; k < 32; ++k) {
        int i = itop - k;
        int a = (i >= ibot) ? A[(size_t)i * NN] : 0;
        int c = (a != 0 && i > j) ? i : -1;
        if (c > best) best = c;
      }
      if (!found && best >= 0) { cur = best; found = true; }
      bool done = found || (ibot <= j + 1);
      if (__syncthreads_and((int)done)) break;
      itop = ibot - 1;
    }
    src[l * NN + j] = cur;
    atomicOr(&lmask[cur >> 5], 1u << (cur & 31));
    __syncthreads();
    if (threadIdx.x < 128) used[bid * 128 + threadIdx.x] = lmask[threadIdx.x];
  } else {
    // ---- deg[row] = sum(adj row) + 1 ; 2 rows per block ----
    const size_t row2 = (size_t)(blockIdx.x - SRC_BLOCKS) * 2;
    const int r = threadIdx.x >> 7;   // 0/1: which row
    const int t = threadIdx.x & 127;
    const int4v* __restrict__ p =
        reinterpret_cast<const int4v*>(adj + (row2 + r) * (size_t)NN);
    int s = 0;
#pragma unroll
    for (int k = 0; k < 8; ++k) {
      int4v v = __builtin_nontemporal_load(&p[t + k * 128]);
      s += v.x + v.y + v.z + v.w;
    }
    for (int off = 32; off > 0; off >>= 1) s += __shfl_down(s, off, 64);
    if ((threadIdx.x & 63) == 0) ws[threadIdx.x >> 6] = s;
    __syncthreads();
    if (threadIdx.x == 0)   deg[row2]     = (float)(ws[0] + ws[1]) + 1.0f;
    if (threadIdx.x == 128) deg[row2 + 1] = (float)(ws[2] + ws[3]) + 1.0f;
  }
}

// ---------------------------------------------------------------------------
// Wf[l,i,:] = W @ feature[i,l,:]  -- computed ONLY for rows with a used-bit.
// With random p=0.5 adjacency only ~16 distinct src values per layer exist,
// so ~128 of the 32768 blocks do work; the rest early-exit (uniform).
// ---------------------------------------------------------------------------
__global__ __launch_bounds__(128) void wf_kernel(const float* __restrict__ feature,
                                                 const float* __restrict__ W,
                                                 const unsigned* __restrict__ used,
                                                 float* __restrict__ Wf) {
  const int i = blockIdx.x;
  const int l = blockIdx.y;
  const int w = i >> 5;
  const unsigned bit = 1u << (i & 31);
  unsigned m = 0;
#pragma unroll
  for (int c = 0; c < 16; ++c) m |= used[(l * 16 + c) * 128 + w];
  if (!(m & bit)) return;   // uniform: depends only on blockIdx

  __shared__ float fbuf[ND];
  if (threadIdx.x < 32)
    reinterpret_cast<float4v*>(fbuf)[threadIdx.x] =
        reinterpret_cast<const float4v*>(feature + ((size_t)i * NL + l) * ND)[threadIdx.x];
  __syncthreads();

  const int d = threadIdx.x;
  float acc = 0.0f;
#pragma unroll 8
  for (int eq = 0; eq < 32; ++eq) {
    float4v wv = reinterpret_cast<const float4v*>(W + (size_t)d * ND)[eq];
    float4v fv = reinterpret_cast<const float4v*>(fbuf)[eq];
    acc += wv.x * fv.x + wv.y * fv.y + wv.z * fv.z + wv.w * fv.w;
  }
  Wf[((size_t)l * NN + i) * ND + d] = acc;
}

// ---------------------------------------------------------------------------
// out[j,l,:] = rsqrt(deg[l,src]*deg[l,j]) * Wf[l,src,:]
// Pure gather-scale-write: one float4 per thread, fully coalesced nontemporal
// stores; Wf reads hit L2 (few distinct rows).
// ---------------------------------------------------------------------------
__global__ __launch_bounds__(256) void out_kernel(const float* __restrict__ Wf,
                                                  const float* __restrict__ deg,
                                                  const int* __restrict__ src,
                                                  float* __restrict__ out) {
  const int g = blockIdx.x * 256 + threadIdx.x;   // float4 index in out
  const int q = g & 31;                           // float4 within d-row
  const int jl = g >> 5;
  const int l = jl & 7;
  const int j = jl >> 3;
  const int s = src[l * NN + j];
  const float sc = rsqrtf(deg[l * NN + s] * deg[l * NN + j]);
  float4v v = reinterpret_cast<const float4v*>(Wf + ((size_t)l * NN + s) * ND)[q];
  v.x *= sc; v.y *= sc; v.z *= sc; v.w *= sc;
  __builtin_nontemporal_store(v, reinterpret_cast<float4v*>(out) + g);
}

// ---------------------------------------------------------------------------
extern "C" void kernel_launch(void* const* d_in, const int* in_sizes, int n_in,
                              void* d_out, int out_size, void* d_ws,
                              size_t ws_size, hipStream_t stream) {
  const float* feature = (const float*)d_in[0];   // [NN, NL, ND] f32
  const float* W       = (const float*)d_in[1];   // [ND, ND]     f32
  const int*   adj     = (const int*)d_in[2];     // [NL, NN, NN] i32
  float* out = (float*)d_out;                     // [NN, NL, ND] f32

  char* ws = (char*)d_ws;
  float*    deg  = (float*)(ws);
  int*      src  = (int*)(ws + 131072);
  unsigned* used = (unsigned*)(ws + 262144);
  float*    Wf   = (float*)(ws + 327680);

  degsrc_kernel<<<SRC_BLOCKS + NL * NN / 2, 256, 0, stream>>>(adj, deg, src, used);
  wf_kernel<<<dim3(NN, NL), 128, 0, stream>>>(feature, W, used, Wf);
  out_kernel<<<NN * NL * ND / 4 / 256, 256, 0, stream>>>(Wf, deg, src, out);
}

// Round 5
// 101.431 us; speedup vs baseline: 1.7067x; 1.0685x over previous
//
#include <hip/hip_runtime.h>
#include <cstddef>

#define NN 4096   // nodes
#define NL 8      // layers
#define ND 128    // feature dim

#define SRC_BLOCKS (NL * (NN / 256))   // 128 src blocks, dispatched FIRST
#define ROWS 4                         // deg rows per block (1 wave / row)
#define WF_BLOCKS 256

typedef int   int4v   __attribute__((ext_vector_type(4)));
typedef float float4v __attribute__((ext_vector_type(4)));

// ws layout (all regions fully rewritten every call -> no zeroing needed):
//   deg  : [NL*NN] f32  @ 0        (128 KB)
//   src  : [NL*NN] i32  @ 131072   (128 KB)
//   wl   : [NL*NN] i32  @ 262144   (128 KB; per-layer distinct-src worklist)
//   count: [NL]    i32  @ 393216
//   Wf   : [NL*NN*ND] f32 @ 409600 (only worklist rows written & read)

// ---------------------------------------------------------------------------
// Fused: blocks [0,128) compute src (latency-bound, hides under the BW-bound
// deg stream); remaining blocks do deg row sums, 4 rows/block, one wave per
// row (wave-reduce only, no LDS), non-temporal int4 loads.
// ---------------------------------------------------------------------------
__global__ __launch_bounds__(256) void degsrc_kernel(const int* __restrict__ adj,
                                                     float* __restrict__ deg,
                                                     int* __restrict__ src) {
  if (blockIdx.x < SRC_BLOCKS) {
    // ---- src[l*NN+j] = max( largest i>j with adj[l,i,j]!=0 , j ) ----
    const int bid = blockIdx.x;
    const int l = bid >> 4;                    // 16 blocks per layer
    const int j = ((bid & 15) << 8) + threadIdx.x;
    const int* __restrict__ A = adj + (size_t)l * NN * NN + j;
    int cur = j;
    bool found = false;
    int itop = NN - 1;
    while (true) {
      int ibot = itop - 31;
      if (ibot < 0) ibot = 0;
      int best = -1;
#pragma unroll
      for (int k = 0; k < 32; ++k) {
        int i = itop - k;
        int a = (i >= ibot) ? A[(size_t)i * NN] : 0;
        int c = (a != 0 && i > j) ? i : -1;
        if (c > best) best = c;
      }
      if (!found && best >= 0) { cur = best; found = true; }
      bool done = found || (ibot <= j + 1);
      if (__syncthreads_and((int)done)) break;
      itop = ibot - 1;
    }
    src[l * NN + j] = cur;
  } else {
    // ---- deg[row] = sum(adj row) + 1 ; ROWS rows/block, 1 wave per row ----
    const size_t row = (size_t)(blockIdx.x - SRC_BLOCKS) * ROWS +
                       (threadIdx.x >> 6);
    const int lane = threadIdx.x & 63;
    const int4v* __restrict__ p =
        reinterpret_cast<const int4v*>(adj + row * (size_t)NN);
    int s = 0;
#pragma unroll
    for (int k = 0; k < 16; ++k) {
      int4v v = __builtin_nontemporal_load(&p[lane + k * 64]);
      s += v.x + v.y + v.z + v.w;
    }
    for (int off = 32; off > 0; off >>= 1) s += __shfl_down(s, off, 64);
    if (lane == 0) deg[row] = (float)s + 1.0f;
  }
}

// ---------------------------------------------------------------------------
// Per layer: worklist of DISTINCT src values (bitmask in LDS -> compact).
// One block per layer; output order nondeterministic but the SET is fixed,
// and downstream writes are idempotent per (l,i) -> deterministic output.
// ---------------------------------------------------------------------------
__global__ __launch_bounds__(256) void compact_kernel(const int* __restrict__ src,
                                                      int* __restrict__ wl,
                                                      int* __restrict__ count) {
  const int l = blockIdx.x;
  __shared__ unsigned mask[NN / 32];
  __shared__ int cnt;
  if (threadIdx.x < NN / 32) mask[threadIdx.x] = 0u;
  if (threadIdx.x == 0) cnt = 0;
  __syncthreads();
  for (int k = threadIdx.x; k < NN; k += 256) {
    int s = src[l * NN + k];
    atomicOr(&mask[s >> 5], 1u << (s & 31));
  }
  __syncthreads();
  if (threadIdx.x < NN / 32) {
    unsigned m = mask[threadIdx.x];
    while (m) {
      int b = __ffs(m) - 1;
      m &= m - 1;
      int pos = atomicAdd(&cnt, 1);
      wl[l * NN + pos] = (threadIdx.x << 5) | b;
    }
  }
  __syncthreads();
  if (threadIdx.x == 0) count[l] = cnt;
}

// ---------------------------------------------------------------------------
// Wf[l,i,:] = W @ feature[i,l,:] for worklist rows only (~130 expected).
// 256 grid-striding blocks; graceful degradation to 32768 entries worst case.
// ---------------------------------------------------------------------------
__global__ __launch_bounds__(128) void wf_kernel(const float* __restrict__ feature,
                                                 const float* __restrict__ W,
                                                 const int* __restrict__ wl,
                                                 const int* __restrict__ count,
                                                 float* __restrict__ Wf) {
  __shared__ int base[NL + 1];
  __shared__ float fbuf[ND];
  if (threadIdx.x == 0) {
    int s = 0;
    for (int l = 0; l < NL; ++l) { base[l] = s; s += count[l]; }
    base[NL] = s;
  }
  __syncthreads();
  const int total = base[NL];
  const int d = threadIdx.x;

  for (int t = blockIdx.x; t < total; t += WF_BLOCKS) {
    int l = 0;
    while (t >= base[l + 1]) ++l;
    const int i = wl[l * NN + (t - base[l])];
    if (threadIdx.x < 32)
      reinterpret_cast<float4v*>(fbuf)[threadIdx.x] =
          reinterpret_cast<const float4v*>(
              feature + ((size_t)i * NL + l) * ND)[threadIdx.x];
    __syncthreads();
    float acc = 0.0f;
#pragma unroll 8
    for (int eq = 0; eq < 32; ++eq) {
      float4v wv = reinterpret_cast<const float4v*>(W + (size_t)d * ND)[eq];
      float4v fv = reinterpret_cast<const float4v*>(fbuf)[eq];
      acc += wv.x * fv.x + wv.y * fv.y + wv.z * fv.z + wv.w * fv.w;
    }
    Wf[((size_t)l * NN + i) * ND + d] = acc;
    __syncthreads();   // fbuf reuse
  }
}

// ---------------------------------------------------------------------------
// out[j,l,:] = rsqrt(deg[l,src]*deg[l,j]) * Wf[l,src,:]
// Gather-scale-write; Wf/deg/src reads are L2-hot, stores non-temporal.
// ---------------------------------------------------------------------------
__global__ __launch_bounds__(256) void out_kernel(const float* __restrict__ Wf,
                                                  const float* __restrict__ deg,
                                                  const int* __restrict__ src,
                                                  float* __restrict__ out) {
  const int g = blockIdx.x * 256 + threadIdx.x;   // float4 index in out
  const int q = g & 31;                           // float4 within d-row
  const int jl = g >> 5;
  const int l = jl & 7;
  const int j = jl >> 3;
  const int s = src[l * NN + j];
  const float sc = rsqrtf(deg[l * NN + s] * deg[l * NN + j]);
  float4v v = reinterpret_cast<const float4v*>(Wf + ((size_t)l * NN + s) * ND)[q];
  v.x *= sc; v.y *= sc; v.z *= sc; v.w *= sc;
  __builtin_nontemporal_store(v, reinterpret_cast<float4v*>(out) + g);
}

// ---------------------------------------------------------------------------
extern "C" void kernel_launch(void* const* d_in, const int* in_sizes, int n_in,
                              void* d_out, int out_size, void* d_ws,
                              size_t ws_size, hipStream_t stream) {
  const float* feature = (const float*)d_in[0];   // [NN, NL, ND] f32
  const float* W       = (const float*)d_in[1];   // [ND, ND]     f32
  const int*   adj     = (const int*)d_in[2];     // [NL, NN, NN] i32
  float* out = (float*)d_out;                     // [NN, NL, ND] f32

  char* ws = (char*)d_ws;
  float* deg   = (float*)(ws);
  int*   src   = (int*)(ws + 131072);
  int*   wl    = (int*)(ws + 262144);
  int*   count = (int*)(ws + 393216);
  float* Wf    = (float*)(ws + 409600);

  degsrc_kernel<<<SRC_BLOCKS + NL * NN / ROWS, 256, 0, stream>>>(adj, deg, src);
  compact_kernel<<<NL, 256, 0, stream>>>(src, wl, count);
  wf_kernel<<<WF_BLOCKS, 128, 0, stream>>>(feature, W, wl, count, Wf);
  out_kernel<<<NN * NL * ND / 4 / 256, 256, 0, stream>>>(Wf, deg, src, out);
}